// Round 2
// baseline (132.984 us; speedup 1.0000x reference)
//
#include <hip/hip_runtime.h>

#define NDIM 64
#define NRANK 8
#define NK 16
#define CSTRIDE 641               // 1 + 64 + 512 + 64
#define ROWSTRIDE (CSTRIDE * NK)  // 10256

// ---- cross-lane helpers -------------------------------------------------

template <int CTRL>
__device__ __forceinline__ float dpp_mov(float x) {
  int t = __builtin_amdgcn_update_dpp(0, __builtin_bit_cast(int, x), CTRL,
                                      0xF, 0xF, true);
  return __builtin_bit_cast(float, t);
}

// sum across the 4 lanes of a quad (lane bits 0..1); result in all 4 lanes
__device__ __forceinline__ void quad_reduce(float& x) {
  x += dpp_mov<0xB1>(x);  // quad_perm [1,0,3,2]  (xor 1)
  x += dpp_mov<0x4E>(x);  // quad_perm [2,3,0,1]  (xor 2)
}

// ---- kernel -------------------------------------------------------------
// One wave per batch row b. lane = k*4 + dg  (k = component, dg = dim group).
// Lane dg handles the contiguous dim chunk d = 16*dg .. 16*dg+15, processed
// as 4 sub-chunks of 4 dims. Per sub-chunk: one 128B W load (8x dwordx4) +
// float4 loads of mu / log-d / label. All loads >= 16B.

__global__ __launch_bounds__(256, 4) void gmm_nll_kernel(
    const float* __restrict__ pred, const float* __restrict__ label,
    float* __restrict__ out, int nb) {
  const int lane = threadIdx.x & 63;
  const int b = (int)((blockIdx.x * blockDim.x + threadIdx.x) >> 6);
  if (b >= nb) return;
  const int k = lane >> 2;
  const int dg = lane & 3;

  const float* comp = pred + (size_t)b * ROWSTRIDE + k * CSTRIDE;
  const float* lbl = label + (size_t)b * NDIM;

  float capL[NRANK][NRANK];  // lower triangle (s <= r) used
  float bv[NRANK];
#pragma unroll
  for (int r = 0; r < NRANK; ++r) {
    bv[r] = 0.f;
#pragma unroll
    for (int s = 0; s <= r; ++s) capL[r][s] = 0.f;
  }
  float mahal1 = 0.f, ldsum = 0.f;

#pragma unroll
  for (int c = 0; c < 4; ++c) {
    const int D0 = dg * 16 + 4 * c;  // first dim of this sub-chunk

    float w_[32];   // W[D0..D0+3][0..7]
    float mu_[4], ld_[4], lb_[4];
    __builtin_memcpy(w_, comp + 1 + NDIM + 8 * D0, 128);
    __builtin_memcpy(mu_, comp + 1 + D0, 16);
    __builtin_memcpy(ld_, comp + 1 + NDIM + NDIM * NRANK + D0, 16);
    __builtin_memcpy(lb_, lbl + D0, 16);

#pragma unroll
    for (int j = 0; j < 4; ++j) {
      float ld = ld_[j];
      float sd = __expf(-0.5f * ld);  // sqrt(1/d)
      float diff = lb_[j] - mu_[j];
      float u = diff * sd;
      mahal1 = fmaf(u, u, mahal1);  // sum diff^2 / d
      ldsum += ld;                  // sum log d

      float v[NRANK];
#pragma unroll
      for (int r = 0; r < NRANK; ++r) v[r] = w_[8 * j + r] * sd;
#pragma unroll
      for (int r = 0; r < NRANK; ++r) {
        bv[r] = fmaf(v[r], u, bv[r]);
#pragma unroll
        for (int s = 0; s <= r; ++s)
          capL[r][s] = fmaf(v[r], v[s], capL[r][s]);
      }
    }
  }

  // reduce partial sums across the 4 dg lanes (quad) — all lanes get totals
  quad_reduce(mahal1);
  quad_reduce(ldsum);
#pragma unroll
  for (int r = 0; r < NRANK; ++r) {
    quad_reduce(bv[r]);
#pragma unroll
    for (int s = 0; s <= r; ++s) quad_reduce(capL[r][s]);
  }

  // cap = I + W^T D^-1 W
#pragma unroll
  for (int r = 0; r < NRANK; ++r) capL[r][r] += 1.0f;

  // in-place Cholesky (lower), fully unrolled; use rsqrt, defer logs
  float invd[NRANK];
  float prodinv = 1.0f;  // prod of 1/L_jj
#pragma unroll
  for (int j = 0; j < NRANK; ++j) {
    float s = capL[j][j];
#pragma unroll
    for (int p = 0; p < j; ++p) s = fmaf(-capL[j][p], capL[j][p], s);
    float inv = __frsqrt_rn(s);  // 1/sqrt(s) = 1/L_jj
    invd[j] = inv;
    prodinv *= inv;
#pragma unroll
    for (int i2 = j + 1; i2 < NRANK; ++i2) {
      float t = capL[i2][j];
#pragma unroll
      for (int p = 0; p < j; ++p) t = fmaf(-capL[i2][p], capL[j][p], t);
      capL[i2][j] = t * inv;
    }
  }
  float logdetL = -__logf(prodinv);  // sum of log(L_jj)

  // forward solve L y = b, accumulate |y|^2
  float y[NRANK];
  float ysq = 0.f;
#pragma unroll
  for (int i2 = 0; i2 < NRANK; ++i2) {
    float t = bv[i2];
#pragma unroll
    for (int j = 0; j < i2; ++j) t = fmaf(-capL[i2][j], y[j], t);
    y[i2] = t * invd[i2];
    ysq = fmaf(y[i2], y[i2], ysq);
  }

  float mahal = mahal1 - ysq;
  float logdet = 2.0f * logdetL + ldsum;
  const float c_dim_log2pi = 117.62413225019810f;  // 64 * log(2*pi)
  float comp_lp = -0.5f * (c_dim_log2pi + logdet + mahal);

  float pi = comp[0];

  // logsumexp over k (lane bits 2..5): lse(pis) and lse(pis + comp_lp)
  float m1 = pi;
  m1 = fmaxf(m1, __shfl_xor(m1, 4));
  m1 = fmaxf(m1, __shfl_xor(m1, 8));
  m1 = fmaxf(m1, __shfl_xor(m1, 16));
  m1 = fmaxf(m1, __shfl_xor(m1, 32));
  float e1 = __expf(pi - m1);
  e1 += __shfl_xor(e1, 4);
  e1 += __shfl_xor(e1, 8);
  e1 += __shfl_xor(e1, 16);
  e1 += __shfl_xor(e1, 32);
  float lse_pi = m1 + __logf(e1);

  float t2 = pi + comp_lp;
  float m2 = t2;
  m2 = fmaxf(m2, __shfl_xor(m2, 4));
  m2 = fmaxf(m2, __shfl_xor(m2, 8));
  m2 = fmaxf(m2, __shfl_xor(m2, 16));
  m2 = fmaxf(m2, __shfl_xor(m2, 32));
  float e2 = __expf(t2 - m2);
  e2 += __shfl_xor(e2, 4);
  e2 += __shfl_xor(e2, 8);
  e2 += __shfl_xor(e2, 16);
  e2 += __shfl_xor(e2, 32);
  float lse_t = m2 + __logf(e2);

  // nll = -(lse(pi + comp_lp) - lse(pi))
  if (lane == 0) out[b] = lse_pi - lse_t;
}

extern "C" void kernel_launch(void* const* d_in, const int* in_sizes, int n_in,
                              void* d_out, int out_size, void* d_ws,
                              size_t ws_size, hipStream_t stream) {
  const float* pred = (const float*)d_in[0];
  const float* label = (const float*)d_in[1];
  float* out = (float*)d_out;
  const int nb = out_size;  // 8192
  const int blocks = (nb + 3) / 4;  // 4 waves (4 rows) per 256-thread block
  gmm_nll_kernel<<<dim3(blocks), dim3(256), 0, stream>>>(pred, label, out, nb);
}

// Round 3
// 92.412 us; speedup vs baseline: 1.4390x; 1.4390x over previous
//
#include <hip/hip_runtime.h>

#define NDIM 64
#define NRANK 8
#define NK 16
#define CSTRIDE 641               // 1 + 64 + 512 + 64
#define ROWSTRIDE (CSTRIDE * NK)  // 10256

// ---- cross-lane helpers -------------------------------------------------

template <int CTRL>
__device__ __forceinline__ float dpp_mov(float x) {
  int t = __builtin_amdgcn_update_dpp(0, __builtin_bit_cast(int, x), CTRL,
                                      0xF, 0xF, true);
  return __builtin_bit_cast(float, t);
}

// sum across the 4 lanes of a quad (lane bits 0..1); result in all 4 lanes
__device__ __forceinline__ void quad_reduce(float& x) {
  x += dpp_mov<0xB1>(x);  // quad_perm [1,0,3,2]  (xor 1)
  x += dpp_mov<0x4E>(x);  // quad_perm [2,3,0,1]  (xor 2)
}

// ---- kernel -------------------------------------------------------------
// One wave per batch row b. lane = k*4 + dg  (k = component, dg = dim group).
// Lane handles dims d = dg + 4*i, i = 0..15 (strided — quad W loads cover a
// contiguous 128B segment per instruction pair). Software-pipelined depth-1
// prefetch keeps VGPR bounded (vs full unroll) so 4 waves/SIMD fit.

__global__ __launch_bounds__(256, 4) void gmm_nll_kernel(
    const float* __restrict__ pred, const float* __restrict__ label,
    float* __restrict__ out, int nb) {
  const int lane = threadIdx.x & 63;
  const int b = (int)((blockIdx.x * blockDim.x + threadIdx.x) >> 6);
  if (b >= nb) return;
  const int k = lane >> 2;
  const int dg = lane & 3;

  const float* comp = pred + (size_t)b * ROWSTRIDE + k * CSTRIDE;
  const float* Wb = comp + 1 + NDIM + dg * NRANK;              // W[dg][0..7]
  const float* mub = comp + 1 + dg;                            // mu[dg]
  const float* ldb = comp + 1 + NDIM + NDIM * NRANK + dg;      // log d[dg]
  const float* lbb = label + (size_t)b * NDIM + dg;

  float capL[NRANK][NRANK];  // lower triangle (s <= r) used
  float bv[NRANK];
#pragma unroll
  for (int r = 0; r < NRANK; ++r) {
    bv[r] = 0.f;
#pragma unroll
    for (int s = 0; s <= r; ++s) capL[r][s] = 0.f;
  }
  float mahal1 = 0.f, ldsum = 0.f;

  // pipeline stage A: current iteration's data
  float4 wa0, wa1;
  float mua, lda, lba;
  __builtin_memcpy(&wa0, Wb, 16);
  __builtin_memcpy(&wa1, Wb + 4, 16);
  mua = mub[0];
  lda = ldb[0];
  lba = lbb[0];

#pragma unroll 2
  for (int i = 0; i < 16; ++i) {
    // prefetch next iteration (depth-1 software pipeline)
    float4 wb0, wb1;
    float mun, ldn, lbn;
    if (i < 15) {
      __builtin_memcpy(&wb0, Wb + 32 * (i + 1), 16);
      __builtin_memcpy(&wb1, Wb + 32 * (i + 1) + 4, 16);
      mun = mub[4 * (i + 1)];
      ldn = ldb[4 * (i + 1)];
      lbn = lbb[4 * (i + 1)];
    } else {
      wb0 = wa0; wb1 = wa1; mun = mua; ldn = lda; lbn = lba;
    }

    // compute current iteration
    float sd = __expf(-0.5f * lda);  // sqrt(1/d)
    float diff = lba - mua;
    float u = diff * sd;
    mahal1 = fmaf(u, u, mahal1);  // sum diff^2 / d
    ldsum += lda;                 // sum log d

    float v[NRANK];
    v[0] = wa0.x * sd; v[1] = wa0.y * sd; v[2] = wa0.z * sd; v[3] = wa0.w * sd;
    v[4] = wa1.x * sd; v[5] = wa1.y * sd; v[6] = wa1.z * sd; v[7] = wa1.w * sd;
#pragma unroll
    for (int r = 0; r < NRANK; ++r) {
      bv[r] = fmaf(v[r], u, bv[r]);
#pragma unroll
      for (int s = 0; s <= r; ++s)
        capL[r][s] = fmaf(v[r], v[s], capL[r][s]);
    }

    // rotate pipeline
    wa0 = wb0; wa1 = wb1; mua = mun; lda = ldn; lba = lbn;
  }

  // reduce partial sums across the 4 dg lanes (quad) — all lanes get totals
  quad_reduce(mahal1);
  quad_reduce(ldsum);
#pragma unroll
  for (int r = 0; r < NRANK; ++r) {
    quad_reduce(bv[r]);
#pragma unroll
    for (int s = 0; s <= r; ++s) quad_reduce(capL[r][s]);
  }

  // cap = I + W^T D^-1 W
#pragma unroll
  for (int r = 0; r < NRANK; ++r) capL[r][r] += 1.0f;

  // in-place Cholesky (lower), fully unrolled; rsqrt + deferred single log
  float invd[NRANK];
  float prodinv = 1.0f;  // prod of 1/L_jj
#pragma unroll
  for (int j = 0; j < NRANK; ++j) {
    float s = capL[j][j];
#pragma unroll
    for (int p = 0; p < j; ++p) s = fmaf(-capL[j][p], capL[j][p], s);
    float inv = __frsqrt_rn(s);  // 1/L_jj
    invd[j] = inv;
    prodinv *= inv;
#pragma unroll
    for (int i2 = j + 1; i2 < NRANK; ++i2) {
      float t = capL[i2][j];
#pragma unroll
      for (int p = 0; p < j; ++p) t = fmaf(-capL[i2][p], capL[j][p], t);
      capL[i2][j] = t * inv;
    }
  }
  float logdetL = -__logf(prodinv);  // sum of log(L_jj)

  // forward solve L y = b, accumulate |y|^2
  float y[NRANK];
  float ysq = 0.f;
#pragma unroll
  for (int i2 = 0; i2 < NRANK; ++i2) {
    float t = bv[i2];
#pragma unroll
    for (int j = 0; j < i2; ++j) t = fmaf(-capL[i2][j], y[j], t);
    y[i2] = t * invd[i2];
    ysq = fmaf(y[i2], y[i2], ysq);
  }

  float mahal = mahal1 - ysq;
  float logdet = 2.0f * logdetL + ldsum;
  const float c_dim_log2pi = 117.62413225019810f;  // 64 * log(2*pi)
  float comp_lp = -0.5f * (c_dim_log2pi + logdet + mahal);

  float pi = comp[0];

  // logsumexp over k (lane bits 2..5): lse(pis) and lse(pis + comp_lp)
  float m1 = pi;
  m1 = fmaxf(m1, __shfl_xor(m1, 4));
  m1 = fmaxf(m1, __shfl_xor(m1, 8));
  m1 = fmaxf(m1, __shfl_xor(m1, 16));
  m1 = fmaxf(m1, __shfl_xor(m1, 32));
  float e1 = __expf(pi - m1);
  e1 += __shfl_xor(e1, 4);
  e1 += __shfl_xor(e1, 8);
  e1 += __shfl_xor(e1, 16);
  e1 += __shfl_xor(e1, 32);
  float lse_pi = m1 + __logf(e1);

  float t2 = pi + comp_lp;
  float m2 = t2;
  m2 = fmaxf(m2, __shfl_xor(m2, 4));
  m2 = fmaxf(m2, __shfl_xor(m2, 8));
  m2 = fmaxf(m2, __shfl_xor(m2, 16));
  m2 = fmaxf(m2, __shfl_xor(m2, 32));
  float e2 = __expf(t2 - m2);
  e2 += __shfl_xor(e2, 4);
  e2 += __shfl_xor(e2, 8);
  e2 += __shfl_xor(e2, 16);
  e2 += __shfl_xor(e2, 32);
  float lse_t = m2 + __logf(e2);

  // nll = -(lse(pi + comp_lp) - lse(pi))
  if (lane == 0) out[b] = lse_pi - lse_t;
}

extern "C" void kernel_launch(void* const* d_in, const int* in_sizes, int n_in,
                              void* d_out, int out_size, void* d_ws,
                              size_t ws_size, hipStream_t stream) {
  const float* pred = (const float*)d_in[0];
  const float* label = (const float*)d_in[1];
  float* out = (float*)d_out;
  const int nb = out_size;  // 8192
  const int blocks = (nb + 3) / 4;  // 4 waves (4 rows) per 256-thread block
  gmm_nll_kernel<<<dim3(blocks), dim3(256), 0, stream>>>(pred, label, out, nb);
}

// Round 4
// 64.728 us; speedup vs baseline: 2.0545x; 1.4277x over previous
//
#include <hip/hip_runtime.h>

#define NDIM 64
#define NRANK 8
#define NK 16
#define CSTRIDE 641                // floats per component: 1 + 64 + 512 + 64
#define ROWSTRIDE (CSTRIDE * NK)   // 10256 floats = 41024 B per row

// ---- DPP helpers --------------------------------------------------------

template <int CTRL>
__device__ __forceinline__ float dpp_mov(float x) {
  int t = __builtin_amdgcn_update_dpp(0, __builtin_bit_cast(int, x), CTRL,
                                      0xF, 0xF, true);
  return __builtin_bit_cast(float, t);
}

// sum across the 16-lane group (lane bits 0..3); all 16 lanes get the total
__device__ __forceinline__ void red16(float& x) {
  x += dpp_mov<0xB1>(x);   // quad_perm [1,0,3,2]  == xor 1
  x += dpp_mov<0x4E>(x);   // quad_perm [2,3,0,1]  == xor 2
  x += dpp_mov<0x141>(x);  // row_half_mirror (i^7) == xor 4 on quad-uniform
  x += dpp_mov<0x140>(x);  // row_mirror      (i^15) == xor 8 on 8-uniform
}

// async global->LDS, 16 B per lane; dst must be wave-uniform, src per-lane
__device__ __forceinline__ void gld_lds16(const float* g, float* l) {
  __builtin_amdgcn_global_load_lds(
      (const __attribute__((address_space(1))) void*)g,
      (__attribute__((address_space(3))) void*)l, 16, 0, 0);
}

// ---- kernel -------------------------------------------------------------
// One row per 256-thread block. Wave w stages row bytes [10240w, 10240w+11264)
// into LDS (linear) via 11 global_load_lds_dwordx4 — deep vmcnt queue gives
// ~11 KB in flight per wave. Wave w then computes components k = 4w..4w+3
// (16 lanes per component, 4 dims per lane), reduces via DPP, and the final
// 16-component logsumexp crosses waves through 32 floats of LDS + one barrier.

__global__ __launch_bounds__(256) void gmm_nll_kernel(
    const float* __restrict__ pred, const float* __restrict__ label,
    float* __restrict__ out, int nb) {
  __shared__ float lds[10528];  // 10496 row floats (j=0..40 KB chunks) + 32 LSE
  const int tid = threadIdx.x;
  const int w = tid >> 6;       // wave id 0..3
  const int lane = tid & 63;
  const int kk = lane >> 4;     // component within wave, 0..3
  const int de = lane & 15;     // dim-group within component
  const int b = blockIdx.x;

  const float* rowg = pred + (size_t)b * ROWSTRIDE;
  const float* lbl = label + (size_t)b * NDIM;

  // label values this lane needs (issued first; done by the vmcnt(0) below)
  float lb_[4];
  lb_[0] = lbl[de];
  lb_[1] = lbl[de + 16];
  lb_[2] = lbl[de + 32];
  lb_[3] = lbl[de + 48];
  asm volatile("" ::: "memory");

  // stage this wave's quarter: chunks j = 10w .. 10w+10 (1 KB each)
  const bool last = (b == nb - 1);
#pragma unroll
  for (int t = 0; t <= 10; ++t) {
    const int j = 10 * w + t;
    const float* src = rowg + j * 256 + lane * 4;
    float* dst = &lds[j * 256];
    if (j < 40) {
      gld_lds16(src, dst);
    } else {
      // j == 40 overruns the row by 960 B; only the last grid row may not
      // read past the buffer — mask to the 4 in-bounds lanes there.
      if (!last) {
        gld_lds16(src, dst);
      } else if (lane < 4) {
        gld_lds16(src, dst);
      }
    }
  }
  asm volatile("s_waitcnt vmcnt(0)" ::: "memory");

  // ---- accumulate cap / b / mahal over this lane's 4 dims ----
  const int k = 4 * w + kk;
  const int C0 = CSTRIDE * k;

  float capL[NRANK][NRANK];  // lower triangle (s <= r) used
  float bv[NRANK];
#pragma unroll
  for (int r = 0; r < NRANK; ++r) {
    bv[r] = 0.f;
#pragma unroll
    for (int s = 0; s <= r; ++s) capL[r][s] = 0.f;
  }
  float mahal1 = 0.f, ldsum = 0.f;

#pragma unroll
  for (int i = 0; i < 4; ++i) {
    const int d = de + 16 * i;
    float mu = lds[C0 + 1 + d];
    float ldv = lds[C0 + 577 + d];  // 1 + 64 + 512
    float sd = __expf(-0.5f * ldv); // sqrt(1/d)
    float diff = lb_[i] - mu;
    float u = diff * sd;
    mahal1 = fmaf(u, u, mahal1);
    ldsum += ldv;

    float v[NRANK];
#pragma unroll
    for (int r = 0; r < NRANK; ++r) v[r] = lds[C0 + 65 + 8 * d + r] * sd;
#pragma unroll
    for (int r = 0; r < NRANK; ++r) {
      bv[r] = fmaf(v[r], u, bv[r]);
#pragma unroll
      for (int s = 0; s <= r; ++s)
        capL[r][s] = fmaf(v[r], v[s], capL[r][s]);
    }
  }

  // reduce the 46 partials across the 16 de-lanes
  red16(mahal1);
  red16(ldsum);
#pragma unroll
  for (int r = 0; r < NRANK; ++r) {
    red16(bv[r]);
#pragma unroll
    for (int s = 0; s <= r; ++s) red16(capL[r][s]);
  }

  // cap = I + W^T D^-1 W
#pragma unroll
  for (int r = 0; r < NRANK; ++r) capL[r][r] += 1.0f;

  // in-place Cholesky (lower), fully unrolled; rsqrt + deferred single log
  float invd[NRANK];
  float prodinv = 1.0f;  // prod of 1/L_jj
#pragma unroll
  for (int j = 0; j < NRANK; ++j) {
    float s = capL[j][j];
#pragma unroll
    for (int p = 0; p < j; ++p) s = fmaf(-capL[j][p], capL[j][p], s);
    float inv = __frsqrt_rn(s);  // 1/L_jj
    invd[j] = inv;
    prodinv *= inv;
#pragma unroll
    for (int i2 = j + 1; i2 < NRANK; ++i2) {
      float t = capL[i2][j];
#pragma unroll
      for (int p = 0; p < j; ++p) t = fmaf(-capL[i2][p], capL[j][p], t);
      capL[i2][j] = t * inv;
    }
  }
  float logdetL = -__logf(prodinv);  // sum log(L_jj)

  // forward solve L y = b, accumulate |y|^2
  float y[NRANK];
  float ysq = 0.f;
#pragma unroll
  for (int i2 = 0; i2 < NRANK; ++i2) {
    float t = bv[i2];
#pragma unroll
    for (int j = 0; j < i2; ++j) t = fmaf(-capL[i2][j], y[j], t);
    y[i2] = t * invd[i2];
    ysq = fmaf(y[i2], y[i2], ysq);
  }

  float mahal = mahal1 - ysq;
  float logdet = 2.0f * logdetL + ldsum;
  const float c_dim_log2pi = 117.62413225019810f;  // 64 * log(2*pi)
  float comp_lp = -0.5f * (c_dim_log2pi + logdet + mahal);

  float pi = lds[C0];

  if (de == 0) {
    lds[10496 + k] = pi;
    lds[10496 + 16 + k] = pi + comp_lp;
  }
  __syncthreads();

  // final logsumexp over the 16 components (wave 0, lanes 0..15)
  if (tid < 16) {
    float p = lds[10496 + tid];
    float t2 = lds[10496 + 16 + tid];

    float m1 = p;
    m1 = fmaxf(m1, dpp_mov<0xB1>(m1));
    m1 = fmaxf(m1, dpp_mov<0x4E>(m1));
    m1 = fmaxf(m1, dpp_mov<0x141>(m1));
    m1 = fmaxf(m1, dpp_mov<0x140>(m1));
    float e1 = __expf(p - m1);
    red16(e1);

    float m2 = t2;
    m2 = fmaxf(m2, dpp_mov<0xB1>(m2));
    m2 = fmaxf(m2, dpp_mov<0x4E>(m2));
    m2 = fmaxf(m2, dpp_mov<0x141>(m2));
    m2 = fmaxf(m2, dpp_mov<0x140>(m2));
    float e2 = __expf(t2 - m2);
    red16(e2);

    if (tid == 0)
      out[b] = (m1 + __logf(e1)) - (m2 + __logf(e2));
  }
}

extern "C" void kernel_launch(void* const* d_in, const int* in_sizes, int n_in,
                              void* d_out, int out_size, void* d_ws,
                              size_t ws_size, hipStream_t stream) {
  const float* pred = (const float*)d_in[0];
  const float* label = (const float*)d_in[1];
  float* out = (float*)d_out;
  const int nb = out_size;  // 8192
  gmm_nll_kernel<<<dim3(nb), dim3(256), 0, stream>>>(pred, label, out, nb);
}